// Round 9
// baseline (197.190 us; speedup 1.0000x reference)
//
#include <hip/hip_runtime.h>
#include <hip/hip_bf16.h>

#define BB   8
#define NN   64
#define EMB  32
#define CD   24
#define HH   100
#define LU   72
#define COUT 248
#define RESO 496
#define FF   128
#define TT   1024            // LUT samples per type over d in [0,2] (d>=2 is masked out)

__device__ __forceinline__ float sp5(float x) {
    // softplus(5x)/5 == 0.2*(max(z,0) + log1p(exp(-|z|))), z=5x
    float z = 5.0f * x;
    float t = __expf(-fabsf(z));
    return 0.2f * (fmaxf(z, 0.0f) + __logf(1.0f + t));
}
__device__ __forceinline__ float4 ld4(const float* p) { return *reinterpret_cast<const float4*>(p); }
__device__ __forceinline__ void st4(float* p, float4 v) { *reinterpret_cast<float4*>(p) = v; }
__device__ __forceinline__ void fma4(float4& a, float s, float4 w) {
    a.x = fmaf(s, w.x, a.x); a.y = fmaf(s, w.y, a.y);
    a.z = fmaf(s, w.z, a.z); a.w = fmaf(s, w.w, a.w);
}

// ---- K0a: W3f_all[t][k][lu] = sum_v rW3[k][lu*32+v]*emb[t][v]; tb_all likewise for rb3
__global__ __launch_bounds__(256) void k0a_w3f(
    const float* __restrict__ rW3, const float* __restrict__ rb3,
    const float* __restrict__ emb, float* __restrict__ W3f_all, float* __restrict__ tb_all)
{
    const int t = blockIdx.x / 10, kc = blockIdx.x % 10;
    __shared__ float embt[EMB];
    if (threadIdx.x < EMB) embt[threadIdx.x] = emb[t * EMB + threadIdx.x];
    __syncthreads();
    for (int idx = threadIdx.x; idx < 10 * LU; idx += 256) {
        const int k = kc * 10 + idx / LU, lu = idx % LU;
        const float* w = rW3 + (size_t)k * (LU * EMB) + lu * EMB;
        float acc = 0.f;
#pragma unroll
        for (int v4 = 0; v4 < EMB / 4; ++v4) {
            float4 wv = ld4(w + 4 * v4);
            acc += wv.x * embt[4 * v4] + wv.y * embt[4 * v4 + 1]
                 + wv.z * embt[4 * v4 + 2] + wv.w * embt[4 * v4 + 3];
        }
        W3f_all[(size_t)t * HH * LU + k * LU + lu] = acc;
    }
    if (kc == 0 && threadIdx.x < LU) {
        const float* w = rb3 + threadIdx.x * EMB;
        float acc = 0.f;
        for (int v = 0; v < EMB; ++v) acc += w[v] * embt[v];
        tb_all[t * LU + threadIdx.x] = acc;
    }
}

// ---- K0b: LUT[type][s][72] at d = s*2/1023; 32-sample chunks, 192 blocks, 25.6KB LDS
__global__ __launch_bounds__(256) void k0b_lut(
    const float* __restrict__ rW1, const float* __restrict__ rb1,
    const float* __restrict__ rW2, const float* __restrict__ rb2,
    const float* __restrict__ W3f_all, const float* __restrict__ tb_all,
    float* __restrict__ LUT)
{
    const int bt = blockIdx.x >> 5, chunk = blockIdx.x & 31;   // 6 types x 32 chunks
    const int s0 = chunk * 32;
    const int tid = threadIdx.x;

    __shared__ __align__(16) float h1T[HH * 32];    // 12800 B  h1T[k][smp]
    __shared__ __align__(16) float h2T[HH * 32];    // 12800 B

    // layer1: thread (ik = sample slot 0..31, ug = u-octant 0..7) -> 13 u each
    {
        const int ik = tid & 31, ug = tid >> 5;
        const float d = (float)(s0 + ik) * (2.0f / 1023.0f);
        float bas[3];
#pragma unroll
        for (int r = 0; r < 3; ++r) {
            float u = fabsf(d - (float)r);
            float c = cosf(1.57079632679489662f * u);
            bas[r] = (u < 1.0f) ? c * c : 0.0f;
        }
#pragma unroll
        for (int uu = 0; uu < 13; ++uu) {
            const int u = ug * 13 + uu;
            if (u < HH) {
                float v = rb1[u] + bas[0] * rW1[u] + bas[1] * rW1[HH + u] + bas[2] * rW1[2 * HH + u];
                h1T[u * 32 + ik] = sp5(v);
            }
        }
    }
    __syncthreads();

    // layer2: thread (ut<25, ig<8): 4u x 4samples register tile; rW2 streamed from L2
    if (tid < 200) {
        const int ut = tid % 25, ig = tid / 25;
        float4 a[4];
        {
            float4 b0 = ld4(&rb2[4 * ut]);
#pragma unroll
            for (int m = 0; m < 4; ++m) a[m] = b0;
        }
#pragma unroll 4
        for (int k = 0; k < HH; ++k) {
            float4 w  = ld4(&rW2[k * HH + 4 * ut]);
            float4 hA = ld4(&h1T[k * 32 + 4 * ig]);
            fma4(a[0], hA.x, w); fma4(a[1], hA.y, w); fma4(a[2], hA.z, w); fma4(a[3], hA.w, w);
        }
#pragma unroll
        for (int m = 0; m < 4; ++m) {
            a[m].x = sp5(a[m].x); a[m].y = sp5(a[m].y); a[m].z = sp5(a[m].z); a[m].w = sp5(a[m].w);
        }
        st4(&h2T[(4 * ut + 0) * 32 + 4 * ig], make_float4(a[0].x, a[1].x, a[2].x, a[3].x));
        st4(&h2T[(4 * ut + 1) * 32 + 4 * ig], make_float4(a[0].y, a[1].y, a[2].y, a[3].y));
        st4(&h2T[(4 * ut + 2) * 32 + 4 * ig], make_float4(a[0].z, a[1].z, a[2].z, a[3].z));
        st4(&h2T[(4 * ut + 3) * 32 + 4 * ig], make_float4(a[0].w, a[1].w, a[2].w, a[3].w));
    }
    __syncthreads();

    // contract: thread (lut<18, ig<8): 4lu x 4samples; W3f streamed from L2
    if (tid < 144) {
        const int lut = tid % 18, ig = tid / 18;
        const float* W3f = W3f_all + (size_t)bt * HH * LU;
        float4 a[4];
        {
            float4 t0 = ld4(&tb_all[bt * LU + 4 * lut]);
#pragma unroll
            for (int m = 0; m < 4; ++m) a[m] = t0;
        }
#pragma unroll 4
        for (int k = 0; k < HH; ++k) {
            float4 w  = ld4(&W3f[k * LU + 4 * lut]);
            float4 hA = ld4(&h2T[k * 32 + 4 * ig]);
            fma4(a[0], hA.x, w); fma4(a[1], hA.y, w); fma4(a[2], hA.z, w); fma4(a[3], hA.w, w);
        }
        const float s = 0.17677669529663688f;   // 1/sqrt(32)
        float* base = LUT + ((size_t)bt * TT + s0) * LU;
#pragma unroll
        for (int m = 0; m < 4; ++m) {
            const int smp = 4 * ig + m;
            st4(&base[smp * LU + 4 * lut], make_float4(a[m].x * s, a[m].y * s, a[m].z * s, a[m].w * s));
        }
    }
}

// ---- K2: block per (b,i): LUT-lerp staging + mask/Y + conv + res-GEMV (no atomics)
__global__ __launch_bounds__(256) void k2_conv(
    const float* __restrict__ xyz, const int* __restrict__ feat,
    const float* __restrict__ emb, const float* __restrict__ LUT,
    const float* __restrict__ resW, const float* __restrict__ resb,
    float* __restrict__ feats, float* __restrict__ x2pre)
{
    const int b = blockIdx.x >> 6, i = blockIdx.x & 63;
    const int tid = threadIdx.x;
    __shared__ __align__(16) float xj[NN * 3];
    __shared__ int   tys[NN];
    __shared__ float dpos[NN];
    __shared__ __align__(16) float mYT[9 * 68];
    __shared__ __align__(16) float tlT[LU * 68];
    __shared__ __align__(16) float fs[COUT];
    __shared__ float inv_s;

    if (tid < 48) st4(&xj[tid * 4], ld4(&xyz[b * NN * 3 + tid * 4]));
    if (tid >= 64 && tid < 128) tys[tid - 64] = feat[b * NN + (tid - 64)];
    if (tid >= 128 && tid < 160) fs[tid - 128] = emb[feat[b * NN + i] * EMB + (tid - 128)];
    __syncthreads();

    if (tid < 64) {
        const int jj = tid;
        float dx = xj[jj * 3 + 0] - xj[i * 3 + 0];
        float dy = xj[jj * 3 + 1] - xj[i * 3 + 1];
        float dz = xj[jj * 3 + 2] - xj[i * 3 + 2];
        float d = sqrtf(dx * dx + dy * dy + dz * dz + 1e-8f);
        float m = (d < 2.0f && jj != i) ? 1.0f : 0.0f;
        float ux = dx / d, uy = dy / d, uz = dz / d;
        mYT[0 * 68 + jj] = m * 0.28209479177f;
        mYT[1 * 68 + jj] = m * 0.48860251190f * uy;
        mYT[2 * 68 + jj] = m * 0.48860251190f * uz;
        mYT[3 * 68 + jj] = m * 0.48860251190f * ux;
        mYT[4 * 68 + jj] = m * 1.09254843059f * ux * uy;
        mYT[5 * 68 + jj] = m * 1.09254843059f * uy * uz;
        mYT[6 * 68 + jj] = m * 0.31539156525f * (3.0f * uz * uz - 1.0f);
        mYT[7 * 68 + jj] = m * 1.09254843059f * ux * uz;
        mYT[8 * 68 + jj] = m * 0.54627421529f * (ux * ux - uy * uy);
        dpos[jj] = fminf(d, 2.0f) * ((float)(TT - 1) * 0.5f);
        unsigned long long bal = __ballot(m > 0.5f);
        if (jj == 0) inv_s = rsqrtf(fmaxf((float)__popcll(bal), 1.0f));
    }
    __syncthreads();

    // LUT linear interpolation -> tlT[lu][jj]  (d>=2 rows are masked later; any value ok)
    for (int idx = tid; idx < NN * LU; idx += 256) {
        const int jj = idx / LU, lu = idx - jj * LU;
        const float pos = dpos[jj];
        int i0 = (int)pos; i0 = (i0 > TT - 2) ? (TT - 2) : i0;
        const float fr = pos - (float)i0;
        const float* rowp = LUT + ((size_t)tys[jj] * TT + i0) * LU + lu;
        const float v0 = rowp[0], v1 = rowp[LU];
        tlT[lu * 68 + jj] = v0 + fr * (v1 - v0);
    }
    __syncthreads();

    if (tid < 216) {
        int l, u, m, yoff;
        if (tid < 24)      { l = 0; u = tid; m = 0; yoff = 0; }
        else if (tid < 96) { int q = tid - 24; l = 1; u = q / 3; m = q % 3; yoff = 1; }
        else               { int q = tid - 96; l = 2; u = q / 5; m = q % 5; yoff = 4; }
        const int lu = l * CD + u, yr = yoff + m;
        float acc = 0.f;
#pragma unroll
        for (int j4 = 0; j4 < 16; ++j4) {
            float4 y = ld4(&mYT[yr * 68 + 4 * j4]);
            float4 t = ld4(&tlT[lu * 68 + 4 * j4]);
            acc += y.x * t.x + y.y * t.y + y.z * t.z + y.w * t.w;
        }
        fs[EMB + tid] = acc * inv_s;
    }
    __syncthreads();

    if (tid < COUT) {
        const size_t row = (size_t)blockIdx.x;
        feats[row * COUT + tid] = fs[tid];
        float acc = resb[tid];
#pragma unroll 4
        for (int k4 = 0; k4 < COUT / 4; ++k4) {
            float4 f4 = ld4(&fs[4 * k4]);
            acc = fmaf(f4.x, resW[(4 * k4 + 0) * COUT + tid], acc);
            acc = fmaf(f4.y, resW[(4 * k4 + 1) * COUT + tid], acc);
            acc = fmaf(f4.z, resW[(4 * k4 + 2) * COUT + tid], acc);
            acc = fmaf(f4.w, resW[(4 * k4 + 3) * COUT + tid], acc);
        }
        x2pre[row * COUT + tid] = acc;
    }
}

// ---- KD: fused tail (stats + norm/relu/pool + head), single block, 1024 threads
__global__ __launch_bounds__(1024) void kd_tail(
    const float* __restrict__ feats, const float* __restrict__ x2pre,
    const float* __restrict__ gamma, const float* __restrict__ beta,
    const float* __restrict__ cW, const float* __restrict__ cb,
    const float* __restrict__ c_gamma, const float* __restrict__ c_beta,
    const float* __restrict__ oW, const float* __restrict__ ob,
    float* __restrict__ out)
{
    const int tid = threadIdx.x;
    __shared__ __align__(16) float psT[RESO * BB];   // 15872 B  psT[c][b]
    __shared__ __align__(16) float part[8 * 1024];   // 32768 B  (stats partials, then head partials)
    __shared__ __align__(16) float musd[2 * COUT];   // 1984 B
    __shared__ __align__(16) float red[FF * BB];     // 4096 B

    // Phase A: column stats of x2pre (512 x 248); thread = (q row-quarter, cs col-slot)
    {
        const int q = tid >> 8, cs = tid & 255;
        float s = 0.f, s2 = 0.f;
        if (cs < COUT) {
            const float* p = x2pre + (size_t)(q * 128) * COUT + cs;
#pragma unroll 4
            for (int r = 0; r < 128; ++r) { const float v = p[(size_t)r * COUT]; s += v; s2 += v * v; }
        }
        part[q * 256 + cs] = s;
        part[1024 + q * 256 + cs] = s2;
    }
    __syncthreads();
    if (tid < COUT) {
        const float s  = part[tid] + part[256 + tid] + part[512 + tid] + part[768 + tid];
        const float s2 = part[1024 + tid] + part[1280 + tid] + part[1536 + tid] + part[1792 + tid];
        const float mu = s * (1.0f / 512.0f);
        const float var = s2 * (1.0f / 512.0f) - mu * mu;
        musd[tid] = mu;
        musd[COUT + tid] = 1.0f / sqrtf(var + 1e-5f);
    }
    __syncthreads();

    // Phase B: pool -> psT[c*8+b]; thread = (b, cs in 0..127) handles channels cs, cs+128, cs+256, cs+384
    {
        const int b = tid >> 7, cs = tid & 127;
        const int c1 = cs + 128;
        const bool f1 = (c1 < COUT);              // cs < 120 -> feats channel; else x2 channel cc1
        const int cc1 = c1 - COUT;
        const int cc2 = cs + 8;                   // channel cs+256 -> x2 index cs+8 (always valid)
        const int cc3 = cs + 136;                 // channel cs+384 -> valid iff cs < 112
        const bool v3 = (cc3 < COUT);
        float mu1 = 0, rs1 = 0, g1 = 0, be1 = 0;
        if (!f1) { mu1 = musd[cc1]; rs1 = musd[COUT + cc1]; g1 = gamma[cc1]; be1 = beta[cc1]; }
        const float mu2 = musd[cc2], rs2 = musd[COUT + cc2], g2 = gamma[cc2], be2 = beta[cc2];
        float mu3 = 0, rs3 = 0, g3 = 0, be3 = 0;
        if (v3) { mu3 = musd[cc3]; rs3 = musd[COUT + cc3]; g3 = gamma[cc3]; be3 = beta[cc3]; }
        float a0 = 0.f, a1 = 0.f, a2 = 0.f, a3 = 0.f;
        const float* fr = feats + (size_t)(b * NN) * COUT;
        const float* xr = x2pre + (size_t)(b * NN) * COUT;
        for (int i = 0; i < NN; ++i) {
            const float* frow = fr + (size_t)i * COUT;
            const float* xrow = xr + (size_t)i * COUT;
            a0 += frow[cs];
            if (f1) a1 += frow[c1];
            else { const float v = (xrow[cc1] - mu1) * rs1 * g1 + be1; a1 += fmaxf(v, 0.f); }
            { const float v = (xrow[cc2] - mu2) * rs2 * g2 + be2; a2 += fmaxf(v, 0.f); }
            if (v3) { const float v = (xrow[cc3] - mu3) * rs3 * g3 + be3; a3 += fmaxf(v, 0.f); }
        }
        const float inv = 1.0f / (float)NN;
        psT[cs * BB + b] = a0 * inv;
        psT[c1 * BB + b] = a1 * inv;
        psT[(cs + 256) * BB + b] = a2 * inv;
        if (v3) psT[(cs + 384) * BB + b] = a3 * inv;
    }
    __syncthreads();

    // Phase C: head — chunked GEMV (8 chunks x 62 k) + register BN(8) + sigmoid
    {
        const int o = tid & 127, chunk = tid >> 7;
        float4 aA = make_float4(0.f, 0.f, 0.f, 0.f), aB = aA;
        const int kbase = chunk * 62;
#pragma unroll 2
        for (int kk = 0; kk < 62; ++kk) {
            const int k = kbase + kk;
            const float w = cW[k * FF + o];
            fma4(aA, w, ld4(&psT[k * BB]));
            fma4(aB, w, ld4(&psT[k * BB + 4]));
        }
        part[0 * 1024 + chunk * FF + o] = aA.x;
        part[1 * 1024 + chunk * FF + o] = aA.y;
        part[2 * 1024 + chunk * FF + o] = aA.z;
        part[3 * 1024 + chunk * FF + o] = aA.w;
        part[4 * 1024 + chunk * FF + o] = aB.x;
        part[5 * 1024 + chunk * FF + o] = aB.y;
        part[6 * 1024 + chunk * FF + o] = aB.z;
        part[7 * 1024 + chunk * FF + o] = aB.w;
    }
    __syncthreads();

    if (tid < FF) {
        float h[8];
#pragma unroll
        for (int q = 0; q < 8; ++q) {
            float s = 0.f;
#pragma unroll
            for (int ch = 0; ch < 8; ++ch) s += part[q * 1024 + ch * FF + tid];
            h[q] = s + cb[tid];
        }
        float mu = 0.f;
#pragma unroll
        for (int q = 0; q < 8; ++q) { h[q] = (h[q] >= 0.f) ? h[q] : 0.01f * h[q]; mu += h[q]; }
        mu *= 0.125f;
        float var = 0.f;
#pragma unroll
        for (int q = 0; q < 8; ++q) { const float dd = h[q] - mu; var += dd * dd; }
        var *= 0.125f;
        const float rstd = 1.0f / sqrtf(var + 1e-5f);
        const float g = c_gamma[tid], be = c_beta[tid], wo = oW[tid];
#pragma unroll
        for (int q = 0; q < 8; ++q) {
            float v = (h[q] - mu) * rstd * g + be;
            h[q] = ((v >= 0.f) ? v : 0.01f * v) * wo;
        }
        st4(&red[tid * 8],     make_float4(h[0], h[1], h[2], h[3]));
        st4(&red[tid * 8 + 4], make_float4(h[4], h[5], h[6], h[7]));
    }
    __syncthreads();
    for (int off = 64; off >= 1; off >>= 1) {
        if (tid < off) {
            float4 x0 = ld4(&red[tid * 8]),     y0 = ld4(&red[(tid + off) * 8]);
            float4 x1 = ld4(&red[tid * 8 + 4]), y1 = ld4(&red[(tid + off) * 8 + 4]);
            st4(&red[tid * 8],     make_float4(x0.x + y0.x, x0.y + y0.y, x0.z + y0.z, x0.w + y0.w));
            st4(&red[tid * 8 + 4], make_float4(x1.x + y1.x, x1.y + y1.y, x1.z + y1.z, x1.w + y1.w));
        }
        __syncthreads();
    }
    if (tid < BB) out[tid] = 1.0f / (1.0f + __expf(-(red[tid] + ob[0])));
}

extern "C" void kernel_launch(void* const* d_in, const int* in_sizes, int n_in,
                              void* d_out, int out_size, void* d_ws, size_t ws_size,
                              hipStream_t stream)
{
    const float* xyz  = (const float*)d_in[0];
    const int*   feat = (const int*)  d_in[1];
    const float* emb  = (const float*)d_in[2];
    const float* rW1  = (const float*)d_in[3];
    const float* rb1  = (const float*)d_in[4];
    const float* rW2  = (const float*)d_in[5];
    const float* rb2  = (const float*)d_in[6];
    const float* rW3  = (const float*)d_in[7];
    const float* rb3  = (const float*)d_in[8];
    const float* resW = (const float*)d_in[9];
    const float* resb = (const float*)d_in[10];
    const float* res_gamma = (const float*)d_in[11];
    const float* res_beta  = (const float*)d_in[12];
    const float* cW   = (const float*)d_in[13];
    const float* cb   = (const float*)d_in[14];
    const float* c_gamma = (const float*)d_in[15];
    const float* c_beta  = (const float*)d_in[16];
    const float* oW   = (const float*)d_in[17];
    const float* ob   = (const float*)d_in[18];
    float* out = (float*)d_out;

    char* ws = (char*)d_ws;
    float* LUT     = (float*)ws;                         // 6*1024*72*4 = 1,769,472 B
    float* W3f_all = (float*)(ws + 1769472);             // 172,800 B
    float* tb_all  = (float*)(ws + 1942272);             // 1,728 B
    float* feats   = (float*)(ws + 1944000);             // 507,904 B
    float* x2pre   = (float*)(ws + 2451904);             // 507,904 B

    k0a_w3f <<<60, 256, 0, stream>>>(rW3, rb3, emb, W3f_all, tb_all);
    k0b_lut <<<192, 256, 0, stream>>>(rW1, rb1, rW2, rb2, W3f_all, tb_all, LUT);
    k2_conv <<<BB * NN, 256, 0, stream>>>(xyz, feat, emb, LUT, resW, resb, feats, x2pre);
    kd_tail <<<1, 1024, 0, stream>>>(feats, x2pre, res_gamma, res_beta,
                                     cW, cb, c_gamma, c_beta, oW, ob, out);
}

// Round 10
// 170.852 us; speedup vs baseline: 1.1542x; 1.1542x over previous
//
#include <hip/hip_runtime.h>
#include <hip/hip_bf16.h>

#define BB   8
#define NN   64
#define EMB  32
#define CD   24
#define HH   100
#define LU   72
#define COUT 248
#define RESO 496
#define FF   128
#define TT   1024            // LUT samples per type over d in [0,2] (d>=2 is masked out)

__device__ __forceinline__ float sp5(float x) {
    // softplus(5x)/5 == 0.2*(max(z,0) + log1p(exp(-|z|))), z=5x
    float z = 5.0f * x;
    float t = __expf(-fabsf(z));
    return 0.2f * (fmaxf(z, 0.0f) + __logf(1.0f + t));
}
__device__ __forceinline__ float4 ld4(const float* p) { return *reinterpret_cast<const float4*>(p); }
__device__ __forceinline__ void st4(float* p, float4 v) { *reinterpret_cast<float4*>(p) = v; }
__device__ __forceinline__ void fma4(float4& a, float s, float4 w) {
    a.x = fmaf(s, w.x, a.x); a.y = fmaf(s, w.y, a.y);
    a.z = fmaf(s, w.z, a.z); a.w = fmaf(s, w.w, a.w);
}

// ---- KA: fused W3f + LUT build. 192 blocks = 6 types x 32 chunks of 32 samples.
//      Each block computes its type's W3f (100x72) into LDS from rW3/emb, then the
//      3-stage radial pipeline for its 32 d-samples. LDS = 28.8+12.8+12.8 ~= 54.7KB.
__global__ __launch_bounds__(256) void ka_lut(
    const float* __restrict__ rW1, const float* __restrict__ rb1,
    const float* __restrict__ rW2, const float* __restrict__ rb2,
    const float* __restrict__ rW3, const float* __restrict__ rb3,
    const float* __restrict__ emb, float* __restrict__ LUT)
{
    const int bt = blockIdx.x >> 5, chunk = blockIdx.x & 31;
    const int s0 = chunk * 32;
    const int tid = threadIdx.x;

    __shared__ __align__(16) float embt[EMB];
    __shared__ __align__(16) float W3fs[HH * LU];   // 28800 B
    __shared__ __align__(16) float tbs[LU];         // 288 B
    __shared__ __align__(16) float h1T[HH * 32];    // 12800 B  h1T[k][smp]
    __shared__ __align__(16) float h2T[HH * 32];    // 12800 B

    if (tid < EMB) embt[tid] = emb[bt * EMB + tid];
    __syncthreads();

    // W3fs[k][lu] = dot(rW3[k, lu*32 : lu*32+32], emb[bt]);  ~28 entries/thread
    for (int idx = tid; idx < HH * LU; idx += 256) {
        const int k = idx / LU, lu = idx - k * LU;
        const float* w = rW3 + (size_t)k * (LU * EMB) + lu * EMB;
        float acc = 0.f;
#pragma unroll
        for (int v4 = 0; v4 < EMB / 4; ++v4) {
            float4 wv = ld4(w + 4 * v4);
            acc += wv.x * embt[4 * v4] + wv.y * embt[4 * v4 + 1]
                 + wv.z * embt[4 * v4 + 2] + wv.w * embt[4 * v4 + 3];
        }
        W3fs[idx] = acc;
    }
    if (tid < LU) {
        const float* w = rb3 + tid * EMB;
        float acc = 0.f;
#pragma unroll
        for (int v = 0; v < EMB; ++v) acc += w[v] * embt[v];
        tbs[tid] = acc;
    }

    // layer1: thread (ik = sample slot 0..31, ug = u-octant 0..7) -> 13 u each
    {
        const int ik = tid & 31, ug = tid >> 5;
        const float d = (float)(s0 + ik) * (2.0f / 1023.0f);
        float bas[3];
#pragma unroll
        for (int r = 0; r < 3; ++r) {
            float u = fabsf(d - (float)r);
            float c = cosf(1.57079632679489662f * u);
            bas[r] = (u < 1.0f) ? c * c : 0.0f;
        }
#pragma unroll
        for (int uu = 0; uu < 13; ++uu) {
            const int u = ug * 13 + uu;
            if (u < HH) {
                float v = rb1[u] + bas[0] * rW1[u] + bas[1] * rW1[HH + u] + bas[2] * rW1[2 * HH + u];
                h1T[u * 32 + ik] = sp5(v);
            }
        }
    }
    __syncthreads();

    // layer2: thread (ut<25, ig<8): 4u x 4samples register tile; rW2 streamed from L2
    if (tid < 200) {
        const int ut = tid % 25, ig = tid / 25;
        float4 a[4];
        {
            float4 b0 = ld4(&rb2[4 * ut]);
#pragma unroll
            for (int m = 0; m < 4; ++m) a[m] = b0;
        }
#pragma unroll 4
        for (int k = 0; k < HH; ++k) {
            float4 w  = ld4(&rW2[k * HH + 4 * ut]);
            float4 hA = ld4(&h1T[k * 32 + 4 * ig]);
            fma4(a[0], hA.x, w); fma4(a[1], hA.y, w); fma4(a[2], hA.z, w); fma4(a[3], hA.w, w);
        }
#pragma unroll
        for (int m = 0; m < 4; ++m) {
            a[m].x = sp5(a[m].x); a[m].y = sp5(a[m].y); a[m].z = sp5(a[m].z); a[m].w = sp5(a[m].w);
        }
        st4(&h2T[(4 * ut + 0) * 32 + 4 * ig], make_float4(a[0].x, a[1].x, a[2].x, a[3].x));
        st4(&h2T[(4 * ut + 1) * 32 + 4 * ig], make_float4(a[0].y, a[1].y, a[2].y, a[3].y));
        st4(&h2T[(4 * ut + 2) * 32 + 4 * ig], make_float4(a[0].z, a[1].z, a[2].z, a[3].z));
        st4(&h2T[(4 * ut + 3) * 32 + 4 * ig], make_float4(a[0].w, a[1].w, a[2].w, a[3].w));
    }
    __syncthreads();

    // contract: thread (lut<18, ig<8): 4lu x 4samples from LDS W3fs/tbs
    if (tid < 144) {
        const int lut = tid % 18, ig = tid / 18;
        float4 a[4];
        {
            float4 t0 = ld4(&tbs[4 * lut]);
#pragma unroll
            for (int m = 0; m < 4; ++m) a[m] = t0;
        }
#pragma unroll 4
        for (int k = 0; k < HH; ++k) {
            float4 w  = ld4(&W3fs[k * LU + 4 * lut]);
            float4 hA = ld4(&h2T[k * 32 + 4 * ig]);
            fma4(a[0], hA.x, w); fma4(a[1], hA.y, w); fma4(a[2], hA.z, w); fma4(a[3], hA.w, w);
        }
        const float s = 0.17677669529663688f;   // 1/sqrt(32)
        float* base = LUT + ((size_t)bt * TT + s0) * LU;
#pragma unroll
        for (int m = 0; m < 4; ++m) {
            const int smp = 4 * ig + m;
            st4(&base[smp * LU + 4 * lut], make_float4(a[m].x * s, a[m].y * s, a[m].z * s, a[m].w * s));
        }
    }
}

// ---- K2: block per (b,i): LUT-lerp staging + mask/Y + conv + res-GEMV (no atomics)
__global__ __launch_bounds__(256) void k2_conv(
    const float* __restrict__ xyz, const int* __restrict__ feat,
    const float* __restrict__ emb, const float* __restrict__ LUT,
    const float* __restrict__ resW, const float* __restrict__ resb,
    float* __restrict__ feats, float* __restrict__ x2pre)
{
    const int b = blockIdx.x >> 6, i = blockIdx.x & 63;
    const int tid = threadIdx.x;
    __shared__ __align__(16) float xj[NN * 3];
    __shared__ int   tys[NN];
    __shared__ float dpos[NN];
    __shared__ __align__(16) float mYT[9 * 68];
    __shared__ __align__(16) float tlT[LU * 68];
    __shared__ __align__(16) float fs[COUT];
    __shared__ float inv_s;

    if (tid < 48) st4(&xj[tid * 4], ld4(&xyz[b * NN * 3 + tid * 4]));
    if (tid >= 64 && tid < 128) tys[tid - 64] = feat[b * NN + (tid - 64)];
    if (tid >= 128 && tid < 160) fs[tid - 128] = emb[feat[b * NN + i] * EMB + (tid - 128)];
    __syncthreads();

    if (tid < 64) {
        const int jj = tid;
        float dx = xj[jj * 3 + 0] - xj[i * 3 + 0];
        float dy = xj[jj * 3 + 1] - xj[i * 3 + 1];
        float dz = xj[jj * 3 + 2] - xj[i * 3 + 2];
        float d = sqrtf(dx * dx + dy * dy + dz * dz + 1e-8f);
        float m = (d < 2.0f && jj != i) ? 1.0f : 0.0f;
        float ux = dx / d, uy = dy / d, uz = dz / d;
        mYT[0 * 68 + jj] = m * 0.28209479177f;
        mYT[1 * 68 + jj] = m * 0.48860251190f * uy;
        mYT[2 * 68 + jj] = m * 0.48860251190f * uz;
        mYT[3 * 68 + jj] = m * 0.48860251190f * ux;
        mYT[4 * 68 + jj] = m * 1.09254843059f * ux * uy;
        mYT[5 * 68 + jj] = m * 1.09254843059f * uy * uz;
        mYT[6 * 68 + jj] = m * 0.31539156525f * (3.0f * uz * uz - 1.0f);
        mYT[7 * 68 + jj] = m * 1.09254843059f * ux * uz;
        mYT[8 * 68 + jj] = m * 0.54627421529f * (ux * ux - uy * uy);
        dpos[jj] = fminf(d, 2.0f) * ((float)(TT - 1) * 0.5f);
        unsigned long long bal = __ballot(m > 0.5f);
        if (jj == 0) inv_s = rsqrtf(fmaxf((float)__popcll(bal), 1.0f));
    }
    __syncthreads();

    // LUT linear interpolation -> tlT[lu][jj]  (d>=2 rows are masked later; any value ok)
    for (int idx = tid; idx < NN * LU; idx += 256) {
        const int jj = idx / LU, lu = idx - jj * LU;
        const float pos = dpos[jj];
        int i0 = (int)pos; i0 = (i0 > TT - 2) ? (TT - 2) : i0;
        const float fr = pos - (float)i0;
        const float* rowp = LUT + ((size_t)tys[jj] * TT + i0) * LU + lu;
        const float v0 = rowp[0], v1 = rowp[LU];
        tlT[lu * 68 + jj] = v0 + fr * (v1 - v0);
    }
    __syncthreads();

    if (tid < 216) {
        int l, u, m, yoff;
        if (tid < 24)      { l = 0; u = tid; m = 0; yoff = 0; }
        else if (tid < 96) { int q = tid - 24; l = 1; u = q / 3; m = q % 3; yoff = 1; }
        else               { int q = tid - 96; l = 2; u = q / 5; m = q % 5; yoff = 4; }
        const int lu = l * CD + u, yr = yoff + m;
        float acc = 0.f;
#pragma unroll
        for (int j4 = 0; j4 < 16; ++j4) {
            float4 y = ld4(&mYT[yr * 68 + 4 * j4]);
            float4 t = ld4(&tlT[lu * 68 + 4 * j4]);
            acc += y.x * t.x + y.y * t.y + y.z * t.z + y.w * t.w;
        }
        fs[EMB + tid] = acc * inv_s;
    }
    __syncthreads();

    if (tid < COUT) {
        const size_t row = (size_t)blockIdx.x;
        feats[row * COUT + tid] = fs[tid];
        float acc = resb[tid];
#pragma unroll 4
        for (int k4 = 0; k4 < COUT / 4; ++k4) {
            float4 f4 = ld4(&fs[4 * k4]);
            acc = fmaf(f4.x, resW[(4 * k4 + 0) * COUT + tid], acc);
            acc = fmaf(f4.y, resW[(4 * k4 + 1) * COUT + tid], acc);
            acc = fmaf(f4.z, resW[(4 * k4 + 2) * COUT + tid], acc);
            acc = fmaf(f4.w, resW[(4 * k4 + 3) * COUT + tid], acc);
        }
        x2pre[row * COUT + tid] = acc;
    }
}

// ---- K4: column stats over 512 rows; block = 8 columns, block-local reduce
__global__ __launch_bounds__(256) void k4_stats(
    const float* __restrict__ x2pre, float* __restrict__ stats)
{
    const int c0 = blockIdx.x * 8;
    const int col = threadIdx.x & 7, r0 = threadIdx.x >> 3;   // 32 row-groups
    float s = 0.f, s2 = 0.f;
#pragma unroll
    for (int p = 0; p < 16; ++p) {
        const int r = r0 + 32 * p;
        const float v = x2pre[(size_t)r * COUT + c0 + col];
        s += v; s2 += v * v;
    }
    __shared__ float rs[256], rq[256];
    rs[threadIdx.x] = s; rq[threadIdx.x] = s2;   // layout [r0][col]
    __syncthreads();
    for (int off = 128; off >= 8; off >>= 1) {
        if (threadIdx.x < off) { rs[threadIdx.x] += rs[threadIdx.x + off]; rq[threadIdx.x] += rq[threadIdx.x + off]; }
        __syncthreads();
    }
    if (threadIdx.x < 8) {
        const float mu  = rs[threadIdx.x] * (1.0f / 512.0f);
        const float var = rq[threadIdx.x] * (1.0f / 512.0f) - mu * mu;
        stats[c0 + threadIdx.x]        = mu;
        stats[COUT + c0 + threadIdx.x] = 1.0f / sqrtf(var + 1e-5f);
    }
}

// ---- K5: 64 blocks (b,seg): disjoint partial pools, no atomics; pp[seg][b][496]
__global__ __launch_bounds__(512) void k5_pool(
    const float* __restrict__ feats, const float* __restrict__ x2pre,
    const float* __restrict__ stats,
    const float* __restrict__ gamma, const float* __restrict__ beta,
    float* __restrict__ pp)
{
    const int b = blockIdx.x >> 3, seg = blockIdx.x & 7;
    const int c = threadIdx.x;
    if (c >= RESO) return;
    float acc = 0.f;
    if (c < COUT) {
#pragma unroll
        for (int ii = 0; ii < 8; ++ii)
            acc += feats[(size_t)(b * NN + seg * 8 + ii) * COUT + c];
    } else {
        const int cc = c - COUT;
        const float mu = stats[cc], rstd = stats[COUT + cc];
        const float g = gamma[cc], be = beta[cc];
#pragma unroll
        for (int ii = 0; ii < 8; ++ii) {
            const float v = (x2pre[(size_t)(b * NN + seg * 8 + ii) * COUT + cc] - mu) * rstd * g + be;
            acc += fmaxf(v, 0.f);
        }
    }
    pp[(seg * BB + b) * RESO + c] = acc * (1.0f / (float)NN);
}

// ---- K6: single block, 1024 threads: sum pp slices + chunked GEMV + register BN(8)
__global__ __launch_bounds__(1024) void k6_head(
    const float* __restrict__ pp,
    const float* __restrict__ cW, const float* __restrict__ cb,
    const float* __restrict__ c_gamma, const float* __restrict__ c_beta,
    const float* __restrict__ oW, const float* __restrict__ ob,
    float* __restrict__ out)
{
    const int tid = threadIdx.x;
    const int o = tid & 127, chunk = tid >> 7;       // 8 chunks x 62 k each
    __shared__ __align__(16) float psT[RESO * BB];   // 15872 B
    __shared__ __align__(16) float part[8 * 8 * FF]; // 32768 B
    __shared__ __align__(16) float red[FF * BB];     // 4096 B
    for (int idx = tid; idx < RESO * BB; idx += 1024) {   // idx = b*496 + k
        const int bb = idx / RESO, k = idx - bb * RESO;
        float s = 0.f;
#pragma unroll
        for (int seg = 0; seg < 8; ++seg) s += pp[seg * (BB * RESO) + idx];
        psT[k * BB + bb] = s;
    }
    __syncthreads();

    float4 aA = make_float4(0.f, 0.f, 0.f, 0.f), aB = aA;
    const int kbase = chunk * 62;
#pragma unroll 2
    for (int kk = 0; kk < 62; ++kk) {
        const int k = kbase + kk;
        const float w = cW[k * FF + o];
        fma4(aA, w, ld4(&psT[k * BB]));
        fma4(aB, w, ld4(&psT[k * BB + 4]));
    }
    part[0 * 1024 + chunk * FF + o] = aA.x;
    part[1 * 1024 + chunk * FF + o] = aA.y;
    part[2 * 1024 + chunk * FF + o] = aA.z;
    part[3 * 1024 + chunk * FF + o] = aA.w;
    part[4 * 1024 + chunk * FF + o] = aB.x;
    part[5 * 1024 + chunk * FF + o] = aB.y;
    part[6 * 1024 + chunk * FF + o] = aB.z;
    part[7 * 1024 + chunk * FF + o] = aB.w;
    __syncthreads();

    if (tid < FF) {
        float h[8];
#pragma unroll
        for (int q = 0; q < 8; ++q) {
            float s = 0.f;
#pragma unroll
            for (int ch = 0; ch < 8; ++ch) s += part[q * 1024 + ch * FF + tid];
            h[q] = s + cb[tid];
        }
        float mu = 0.f;
#pragma unroll
        for (int q = 0; q < 8; ++q) { h[q] = (h[q] >= 0.f) ? h[q] : 0.01f * h[q]; mu += h[q]; }
        mu *= 0.125f;
        float var = 0.f;
#pragma unroll
        for (int q = 0; q < 8; ++q) { const float dd = h[q] - mu; var += dd * dd; }
        var *= 0.125f;
        const float rstd = 1.0f / sqrtf(var + 1e-5f);
        const float g = c_gamma[tid], be = c_beta[tid], wo = oW[tid];
#pragma unroll
        for (int q = 0; q < 8; ++q) {
            float v = (h[q] - mu) * rstd * g + be;
            h[q] = ((v >= 0.f) ? v : 0.01f * v) * wo;
        }
        st4(&red[tid * 8],     make_float4(h[0], h[1], h[2], h[3]));
        st4(&red[tid * 8 + 4], make_float4(h[4], h[5], h[6], h[7]));
    }
    __syncthreads();
    for (int off = 64; off >= 1; off >>= 1) {
        if (tid < off) {
            float4 x0 = ld4(&red[tid * 8]),     y0 = ld4(&red[(tid + off) * 8]);
            float4 x1 = ld4(&red[tid * 8 + 4]), y1 = ld4(&red[(tid + off) * 8 + 4]);
            st4(&red[tid * 8],     make_float4(x0.x + y0.x, x0.y + y0.y, x0.z + y0.z, x0.w + y0.w));
            st4(&red[tid * 8 + 4], make_float4(x1.x + y1.x, x1.y + y1.y, x1.z + y1.z, x1.w + y1.w));
        }
        __syncthreads();
    }
    if (tid < BB) out[tid] = 1.0f / (1.0f + __expf(-(red[tid] + ob[0])));
}

extern "C" void kernel_launch(void* const* d_in, const int* in_sizes, int n_in,
                              void* d_out, int out_size, void* d_ws, size_t ws_size,
                              hipStream_t stream)
{
    const float* xyz  = (const float*)d_in[0];
    const int*   feat = (const int*)  d_in[1];
    const float* emb  = (const float*)d_in[2];
    const float* rW1  = (const float*)d_in[3];
    const float* rb1  = (const float*)d_in[4];
    const float* rW2  = (const float*)d_in[5];
    const float* rb2  = (const float*)d_in[6];
    const float* rW3  = (const float*)d_in[7];
    const float* rb3  = (const float*)d_in[8];
    const float* resW = (const float*)d_in[9];
    const float* resb = (const float*)d_in[10];
    const float* res_gamma = (const float*)d_in[11];
    const float* res_beta  = (const float*)d_in[12];
    const float* cW   = (const float*)d_in[13];
    const float* cb   = (const float*)d_in[14];
    const float* c_gamma = (const float*)d_in[15];
    const float* c_beta  = (const float*)d_in[16];
    const float* oW   = (const float*)d_in[17];
    const float* ob   = (const float*)d_in[18];
    float* out = (float*)d_out;

    char* ws = (char*)d_ws;
    float* LUT   = (float*)ws;                           // 6*1024*72*4 = 1,769,472 B
    float* feats = (float*)(ws + 1769472);               // 507,904 B
    float* x2pre = (float*)(ws + 2277376);               // 507,904 B
    float* stats = (float*)(ws + 2785280);               // 1,984 B
    float* pp    = (float*)(ws + 2787264);               // 8*8*496*4 = 126,976 B

    ka_lut  <<<192, 256, 0, stream>>>(rW1, rb1, rW2, rb2, rW3, rb3, emb, LUT);
    k2_conv <<<BB * NN, 256, 0, stream>>>(xyz, feat, emb, LUT, resW, resb, feats, x2pre);
    k4_stats<<<31, 256, 0, stream>>>(x2pre, stats);
    k5_pool <<<BB * 8, 512, 0, stream>>>(feats, x2pre, stats, res_gamma, res_beta, pp);
    k6_head <<<1, 1024, 0, stream>>>(pp, cW, cb, c_gamma, c_beta, oW, ob, out);
}

// Round 11
// 155.349 us; speedup vs baseline: 1.2693x; 1.0998x over previous
//
#include <hip/hip_runtime.h>
#include <hip/hip_bf16.h>

#define BB   8
#define NN   64
#define EMB  32
#define CD   24
#define HH   100
#define LU   72
#define COUT 248
#define RESO 496
#define FF   128
#define TT   1024            // LUT samples per type over d in [0,2] (d>=2 is masked out)

__device__ __forceinline__ float sp5(float x) {
    // softplus(5x)/5 == 0.2*(max(z,0) + log1p(exp(-|z|))), z=5x
    float z = 5.0f * x;
    float t = __expf(-fabsf(z));
    return 0.2f * (fmaxf(z, 0.0f) + __logf(1.0f + t));
}
__device__ __forceinline__ float4 ld4(const float* p) { return *reinterpret_cast<const float4*>(p); }
__device__ __forceinline__ void st4(float* p, float4 v) { *reinterpret_cast<float4*>(p) = v; }
__device__ __forceinline__ void fma4(float4& a, float s, float4 w) {
    a.x = fmaf(s, w.x, a.x); a.y = fmaf(s, w.y, a.y);
    a.z = fmaf(s, w.z, a.z); a.w = fmaf(s, w.w, a.w);
}

// ---- K0a: W3f_all[t][k][lu] = sum_v rW3[k][lu*32+v]*emb[t][v]; tb_all likewise for rb3
__global__ __launch_bounds__(256) void k0a_w3f(
    const float* __restrict__ rW3, const float* __restrict__ rb3,
    const float* __restrict__ emb, float* __restrict__ W3f_all, float* __restrict__ tb_all)
{
    const int t = blockIdx.x / 10, kc = blockIdx.x % 10;
    __shared__ float embt[EMB];
    if (threadIdx.x < EMB) embt[threadIdx.x] = emb[t * EMB + threadIdx.x];
    __syncthreads();
    for (int idx = threadIdx.x; idx < 10 * LU; idx += 256) {
        const int k = kc * 10 + idx / LU, lu = idx % LU;
        const float* w = rW3 + (size_t)k * (LU * EMB) + lu * EMB;
        float acc = 0.f;
#pragma unroll
        for (int v4 = 0; v4 < EMB / 4; ++v4) {
            float4 wv = ld4(w + 4 * v4);
            acc += wv.x * embt[4 * v4] + wv.y * embt[4 * v4 + 1]
                 + wv.z * embt[4 * v4 + 2] + wv.w * embt[4 * v4 + 3];
        }
        W3f_all[(size_t)t * HH * LU + k * LU + lu] = acc;
    }
    if (kc == 0 && threadIdx.x < LU) {
        const float* w = rb3 + threadIdx.x * EMB;
        float acc = 0.f;
        for (int v = 0; v < EMB; ++v) acc += w[v] * embt[v];
        tb_all[t * LU + threadIdx.x] = acc;
    }
}

// ---- K0b: LUT[type][s][72] at d = s*2/1023; 32-sample chunks, 192 blocks, 25.6KB LDS
//      weights (rW2, W3f, rb2, tb) streamed from L2, not staged
__global__ __launch_bounds__(256) void k0b_lut(
    const float* __restrict__ rW1, const float* __restrict__ rb1,
    const float* __restrict__ rW2, const float* __restrict__ rb2,
    const float* __restrict__ W3f_all, const float* __restrict__ tb_all,
    float* __restrict__ LUT)
{
    const int bt = blockIdx.x >> 5, chunk = blockIdx.x & 31;   // 6 types x 32 chunks
    const int s0 = chunk * 32;
    const int tid = threadIdx.x;

    __shared__ __align__(16) float h1T[HH * 32];    // 12800 B  h1T[k][smp]
    __shared__ __align__(16) float h2T[HH * 32];    // 12800 B

    // layer1: thread (ik = sample slot 0..31, ug = u-octant 0..7) -> 13 u each
    {
        const int ik = tid & 31, ug = tid >> 5;
        const float d = (float)(s0 + ik) * (2.0f / 1023.0f);
        float bas[3];
#pragma unroll
        for (int r = 0; r < 3; ++r) {
            float u = fabsf(d - (float)r);
            float c = cosf(1.57079632679489662f * u);
            bas[r] = (u < 1.0f) ? c * c : 0.0f;
        }
#pragma unroll
        for (int uu = 0; uu < 13; ++uu) {
            const int u = ug * 13 + uu;
            if (u < HH) {
                float v = rb1[u] + bas[0] * rW1[u] + bas[1] * rW1[HH + u] + bas[2] * rW1[2 * HH + u];
                h1T[u * 32 + ik] = sp5(v);
            }
        }
    }
    __syncthreads();

    // layer2: thread (ut<25, ig<8): 4u x 4samples register tile; rW2 streamed from L2
    if (tid < 200) {
        const int ut = tid % 25, ig = tid / 25;
        float4 a[4];
        {
            float4 b0 = ld4(&rb2[4 * ut]);
#pragma unroll
            for (int m = 0; m < 4; ++m) a[m] = b0;
        }
#pragma unroll 4
        for (int k = 0; k < HH; ++k) {
            float4 w  = ld4(&rW2[k * HH + 4 * ut]);
            float4 hA = ld4(&h1T[k * 32 + 4 * ig]);
            fma4(a[0], hA.x, w); fma4(a[1], hA.y, w); fma4(a[2], hA.z, w); fma4(a[3], hA.w, w);
        }
#pragma unroll
        for (int m = 0; m < 4; ++m) {
            a[m].x = sp5(a[m].x); a[m].y = sp5(a[m].y); a[m].z = sp5(a[m].z); a[m].w = sp5(a[m].w);
        }
        st4(&h2T[(4 * ut + 0) * 32 + 4 * ig], make_float4(a[0].x, a[1].x, a[2].x, a[3].x));
        st4(&h2T[(4 * ut + 1) * 32 + 4 * ig], make_float4(a[0].y, a[1].y, a[2].y, a[3].y));
        st4(&h2T[(4 * ut + 2) * 32 + 4 * ig], make_float4(a[0].z, a[1].z, a[2].z, a[3].z));
        st4(&h2T[(4 * ut + 3) * 32 + 4 * ig], make_float4(a[0].w, a[1].w, a[2].w, a[3].w));
    }
    __syncthreads();

    // contract: thread (lut<18, ig<8): 4lu x 4samples; W3f streamed from L2
    if (tid < 144) {
        const int lut = tid % 18, ig = tid / 18;
        const float* W3f = W3f_all + (size_t)bt * HH * LU;
        float4 a[4];
        {
            float4 t0 = ld4(&tb_all[bt * LU + 4 * lut]);
#pragma unroll
            for (int m = 0; m < 4; ++m) a[m] = t0;
        }
#pragma unroll 4
        for (int k = 0; k < HH; ++k) {
            float4 w  = ld4(&W3f[k * LU + 4 * lut]);
            float4 hA = ld4(&h2T[k * 32 + 4 * ig]);
            fma4(a[0], hA.x, w); fma4(a[1], hA.y, w); fma4(a[2], hA.z, w); fma4(a[3], hA.w, w);
        }
        const float s = 0.17677669529663688f;   // 1/sqrt(32)
        float* base = LUT + ((size_t)bt * TT + s0) * LU;
#pragma unroll
        for (int m = 0; m < 4; ++m) {
            const int smp = 4 * ig + m;
            st4(&base[smp * LU + 4 * lut], make_float4(a[m].x * s, a[m].y * s, a[m].z * s, a[m].w * s));
        }
    }
}

// ---- K2: block per (b,i): LUT-lerp staging + mask/Y + conv + res-GEMV (no atomics)
__global__ __launch_bounds__(256) void k2_conv(
    const float* __restrict__ xyz, const int* __restrict__ feat,
    const float* __restrict__ emb, const float* __restrict__ LUT,
    const float* __restrict__ resW, const float* __restrict__ resb,
    float* __restrict__ feats, float* __restrict__ x2pre)
{
    const int b = blockIdx.x >> 6, i = blockIdx.x & 63;
    const int tid = threadIdx.x;
    __shared__ __align__(16) float xj[NN * 3];
    __shared__ int   tys[NN];
    __shared__ float dpos[NN];
    __shared__ __align__(16) float mYT[9 * 68];
    __shared__ __align__(16) float tlT[LU * 68];
    __shared__ __align__(16) float fs[COUT];
    __shared__ float inv_s;

    if (tid < 48) st4(&xj[tid * 4], ld4(&xyz[b * NN * 3 + tid * 4]));
    if (tid >= 64 && tid < 128) tys[tid - 64] = feat[b * NN + (tid - 64)];
    if (tid >= 128 && tid < 160) fs[tid - 128] = emb[feat[b * NN + i] * EMB + (tid - 128)];
    __syncthreads();

    if (tid < 64) {
        const int jj = tid;
        float dx = xj[jj * 3 + 0] - xj[i * 3 + 0];
        float dy = xj[jj * 3 + 1] - xj[i * 3 + 1];
        float dz = xj[jj * 3 + 2] - xj[i * 3 + 2];
        float d = sqrtf(dx * dx + dy * dy + dz * dz + 1e-8f);
        float m = (d < 2.0f && jj != i) ? 1.0f : 0.0f;
        float ux = dx / d, uy = dy / d, uz = dz / d;
        mYT[0 * 68 + jj] = m * 0.28209479177f;
        mYT[1 * 68 + jj] = m * 0.48860251190f * uy;
        mYT[2 * 68 + jj] = m * 0.48860251190f * uz;
        mYT[3 * 68 + jj] = m * 0.48860251190f * ux;
        mYT[4 * 68 + jj] = m * 1.09254843059f * ux * uy;
        mYT[5 * 68 + jj] = m * 1.09254843059f * uy * uz;
        mYT[6 * 68 + jj] = m * 0.31539156525f * (3.0f * uz * uz - 1.0f);
        mYT[7 * 68 + jj] = m * 1.09254843059f * ux * uz;
        mYT[8 * 68 + jj] = m * 0.54627421529f * (ux * ux - uy * uy);
        dpos[jj] = fminf(d, 2.0f) * ((float)(TT - 1) * 0.5f);
        unsigned long long bal = __ballot(m > 0.5f);
        if (jj == 0) inv_s = rsqrtf(fmaxf((float)__popcll(bal), 1.0f));
    }
    __syncthreads();

    // LUT linear interpolation -> tlT[lu][jj]  (d>=2 rows are masked later; any value ok)
    for (int idx = tid; idx < NN * LU; idx += 256) {
        const int jj = idx / LU, lu = idx - jj * LU;
        const float pos = dpos[jj];
        int i0 = (int)pos; i0 = (i0 > TT - 2) ? (TT - 2) : i0;
        const float fr = pos - (float)i0;
        const float* rowp = LUT + ((size_t)tys[jj] * TT + i0) * LU + lu;
        const float v0 = rowp[0], v1 = rowp[LU];
        tlT[lu * 68 + jj] = v0 + fr * (v1 - v0);
    }
    __syncthreads();

    if (tid < 216) {
        int l, u, m, yoff;
        if (tid < 24)      { l = 0; u = tid; m = 0; yoff = 0; }
        else if (tid < 96) { int q = tid - 24; l = 1; u = q / 3; m = q % 3; yoff = 1; }
        else               { int q = tid - 96; l = 2; u = q / 5; m = q % 5; yoff = 4; }
        const int lu = l * CD + u, yr = yoff + m;
        float acc = 0.f;
#pragma unroll
        for (int j4 = 0; j4 < 16; ++j4) {
            float4 y = ld4(&mYT[yr * 68 + 4 * j4]);
            float4 t = ld4(&tlT[lu * 68 + 4 * j4]);
            acc += y.x * t.x + y.y * t.y + y.z * t.z + y.w * t.w;
        }
        fs[EMB + tid] = acc * inv_s;
    }
    __syncthreads();

    if (tid < COUT) {
        const size_t row = (size_t)blockIdx.x;
        feats[row * COUT + tid] = fs[tid];
        float acc = resb[tid];
#pragma unroll 4
        for (int k4 = 0; k4 < COUT / 4; ++k4) {
            float4 f4 = ld4(&fs[4 * k4]);
            acc = fmaf(f4.x, resW[(4 * k4 + 0) * COUT + tid], acc);
            acc = fmaf(f4.y, resW[(4 * k4 + 1) * COUT + tid], acc);
            acc = fmaf(f4.z, resW[(4 * k4 + 2) * COUT + tid], acc);
            acc = fmaf(f4.w, resW[(4 * k4 + 3) * COUT + tid], acc);
        }
        x2pre[row * COUT + tid] = acc;
    }
}

// ---- K4: column stats over 512 rows; block = 8 columns, block-local reduce
__global__ __launch_bounds__(256) void k4_stats(
    const float* __restrict__ x2pre, float* __restrict__ stats)
{
    const int c0 = blockIdx.x * 8;
    const int col = threadIdx.x & 7, r0 = threadIdx.x >> 3;   // 32 row-groups
    float s = 0.f, s2 = 0.f;
#pragma unroll
    for (int p = 0; p < 16; ++p) {
        const int r = r0 + 32 * p;
        const float v = x2pre[(size_t)r * COUT + c0 + col];
        s += v; s2 += v * v;
    }
    __shared__ float rs[256], rq[256];
    rs[threadIdx.x] = s; rq[threadIdx.x] = s2;   // layout [r0][col]
    __syncthreads();
    for (int off = 128; off >= 8; off >>= 1) {
        if (threadIdx.x < off) { rs[threadIdx.x] += rs[threadIdx.x + off]; rq[threadIdx.x] += rq[threadIdx.x + off]; }
        __syncthreads();
    }
    if (threadIdx.x < 8) {
        const float mu  = rs[threadIdx.x] * (1.0f / 512.0f);
        const float var = rq[threadIdx.x] * (1.0f / 512.0f) - mu * mu;
        stats[c0 + threadIdx.x]        = mu;
        stats[COUT + c0 + threadIdx.x] = 1.0f / sqrtf(var + 1e-5f);
    }
}

// ---- K5: 64 blocks (b,seg): disjoint partial pools, no atomics; pp[seg][b][496]
__global__ __launch_bounds__(512) void k5_pool(
    const float* __restrict__ feats, const float* __restrict__ x2pre,
    const float* __restrict__ stats,
    const float* __restrict__ gamma, const float* __restrict__ beta,
    float* __restrict__ pp)
{
    const int b = blockIdx.x >> 3, seg = blockIdx.x & 7;
    const int c = threadIdx.x;
    if (c >= RESO) return;
    float acc = 0.f;
    if (c < COUT) {
#pragma unroll
        for (int ii = 0; ii < 8; ++ii)
            acc += feats[(size_t)(b * NN + seg * 8 + ii) * COUT + c];
    } else {
        const int cc = c - COUT;
        const float mu = stats[cc], rstd = stats[COUT + cc];
        const float g = gamma[cc], be = beta[cc];
#pragma unroll
        for (int ii = 0; ii < 8; ++ii) {
            const float v = (x2pre[(size_t)(b * NN + seg * 8 + ii) * COUT + cc] - mu) * rstd * g + be;
            acc += fmaxf(v, 0.f);
        }
    }
    pp[(seg * BB + b) * RESO + c] = acc * (1.0f / (float)NN);
}

// ---- K6: single block, 1024 threads: sum pp slices + chunked GEMV + register BN(8)
__global__ __launch_bounds__(1024) void k6_head(
    const float* __restrict__ pp,
    const float* __restrict__ cW, const float* __restrict__ cb,
    const float* __restrict__ c_gamma, const float* __restrict__ c_beta,
    const float* __restrict__ oW, const float* __restrict__ ob,
    float* __restrict__ out)
{
    const int tid = threadIdx.x;
    const int o = tid & 127, chunk = tid >> 7;       // 8 chunks x 62 k each
    __shared__ __align__(16) float psT[RESO * BB];   // 15872 B
    __shared__ __align__(16) float part[8 * 8 * FF]; // 32768 B
    __shared__ __align__(16) float red[FF * BB];     // 4096 B
    for (int idx = tid; idx < RESO * BB; idx += 1024) {   // idx = b*496 + k
        const int bb = idx / RESO, k = idx - bb * RESO;
        float s = 0.f;
#pragma unroll
        for (int seg = 0; seg < 8; ++seg) s += pp[seg * (BB * RESO) + idx];
        psT[k * BB + bb] = s;
    }
    __syncthreads();

    float4 aA = make_float4(0.f, 0.f, 0.f, 0.f), aB = aA;
    const int kbase = chunk * 62;
#pragma unroll 2
    for (int kk = 0; kk < 62; ++kk) {
        const int k = kbase + kk;
        const float w = cW[k * FF + o];
        fma4(aA, w, ld4(&psT[k * BB]));
        fma4(aB, w, ld4(&psT[k * BB + 4]));
    }
    part[0 * 1024 + chunk * FF + o] = aA.x;
    part[1 * 1024 + chunk * FF + o] = aA.y;
    part[2 * 1024 + chunk * FF + o] = aA.z;
    part[3 * 1024 + chunk * FF + o] = aA.w;
    part[4 * 1024 + chunk * FF + o] = aB.x;
    part[5 * 1024 + chunk * FF + o] = aB.y;
    part[6 * 1024 + chunk * FF + o] = aB.z;
    part[7 * 1024 + chunk * FF + o] = aB.w;
    __syncthreads();

    if (tid < FF) {
        float h[8];
#pragma unroll
        for (int q = 0; q < 8; ++q) {
            float s = 0.f;
#pragma unroll
            for (int ch = 0; ch < 8; ++ch) s += part[q * 1024 + ch * FF + tid];
            h[q] = s + cb[tid];
        }
        float mu = 0.f;
#pragma unroll
        for (int q = 0; q < 8; ++q) { h[q] = (h[q] >= 0.f) ? h[q] : 0.01f * h[q]; mu += h[q]; }
        mu *= 0.125f;
        float var = 0.f;
#pragma unroll
        for (int q = 0; q < 8; ++q) { const float dd = h[q] - mu; var += dd * dd; }
        var *= 0.125f;
        const float rstd = 1.0f / sqrtf(var + 1e-5f);
        const float g = c_gamma[tid], be = c_beta[tid], wo = oW[tid];
#pragma unroll
        for (int q = 0; q < 8; ++q) {
            float v = (h[q] - mu) * rstd * g + be;
            h[q] = ((v >= 0.f) ? v : 0.01f * v) * wo;
        }
        st4(&red[tid * 8],     make_float4(h[0], h[1], h[2], h[3]));
        st4(&red[tid * 8 + 4], make_float4(h[4], h[5], h[6], h[7]));
    }
    __syncthreads();
    for (int off = 64; off >= 1; off >>= 1) {
        if (tid < off) {
            float4 x0 = ld4(&red[tid * 8]),     y0 = ld4(&red[(tid + off) * 8]);
            float4 x1 = ld4(&red[tid * 8 + 4]), y1 = ld4(&red[(tid + off) * 8 + 4]);
            st4(&red[tid * 8],     make_float4(x0.x + y0.x, x0.y + y0.y, x0.z + y0.z, x0.w + y0.w));
            st4(&red[tid * 8 + 4], make_float4(x1.x + y1.x, x1.y + y1.y, x1.z + y1.z, x1.w + y1.w));
        }
        __syncthreads();
    }
    if (tid < BB) out[tid] = 1.0f / (1.0f + __expf(-(red[tid] + ob[0])));
}

extern "C" void kernel_launch(void* const* d_in, const int* in_sizes, int n_in,
                              void* d_out, int out_size, void* d_ws, size_t ws_size,
                              hipStream_t stream)
{
    const float* xyz  = (const float*)d_in[0];
    const int*   feat = (const int*)  d_in[1];
    const float* emb  = (const float*)d_in[2];
    const float* rW1  = (const float*)d_in[3];
    const float* rb1  = (const float*)d_in[4];
    const float* rW2  = (const float*)d_in[5];
    const float* rb2  = (const float*)d_in[6];
    const float* rW3  = (const float*)d_in[7];
    const float* rb3  = (const float*)d_in[8];
    const float* resW = (const float*)d_in[9];
    const float* resb = (const float*)d_in[10];
    const float* res_gamma = (const float*)d_in[11];
    const float* res_beta  = (const float*)d_in[12];
    const float* cW   = (const float*)d_in[13];
    const float* cb   = (const float*)d_in[14];
    const float* c_gamma = (const float*)d_in[15];
    const float* c_beta  = (const float*)d_in[16];
    const float* oW   = (const float*)d_in[17];
    const float* ob   = (const float*)d_in[18];
    float* out = (float*)d_out;

    char* ws = (char*)d_ws;
    float* LUT     = (float*)ws;                         // 6*1024*72*4 = 1,769,472 B
    float* W3f_all = (float*)(ws + 1769472);             // 172,800 B
    float* tb_all  = (float*)(ws + 1942272);             // 1,728 B
    float* feats   = (float*)(ws + 1944000);             // 507,904 B
    float* x2pre   = (float*)(ws + 2451904);             // 507,904 B
    float* stats   = (float*)(ws + 2959808);             // 1,984 B
    float* pp      = (float*)(ws + 2961792);             // 8*8*496*4 = 126,976 B

    k0a_w3f <<<60, 256, 0, stream>>>(rW3, rb3, emb, W3f_all, tb_all);
    k0b_lut <<<192, 256, 0, stream>>>(rW1, rb1, rW2, rb2, W3f_all, tb_all, LUT);
    k2_conv <<<BB * NN, 256, 0, stream>>>(xyz, feat, emb, LUT, resW, resb, feats, x2pre);
    k4_stats<<<31, 256, 0, stream>>>(x2pre, stats);
    k5_pool <<<BB * 8, 512, 0, stream>>>(feats, x2pre, stats, res_gamma, res_beta, pp);
    k6_head <<<1, 1024, 0, stream>>>(pp, cW, cb, c_gamma, c_beta, oW, ob, out);
}